// Round 1
// baseline (15233.682 us; speedup 1.0000x reference)
//
#include <hip/hip_runtime.h>
#include <hip/hip_bf16.h>
#include <math.h>

#define NT 512
#define S 49
#define CH 384
#define NHD 12
#define HDM 32
#define HIDN 1536

#define WIN_STR 388   // float stride, win rows
#define ALN_STR 194   // u32 stride (= 388 bf16) for packed LN output
#define QKV_STR 37    // float stride, q/k/v/o per-head tiles  (5c mod32 -> conflict-free)
#define SC_STR  56    // float stride, scores
#define WQ_STR  70    // float stride, staged K=64 weight tiles (2-way = free)
#define WO_STR  33    // float stride, staged K=32 out_w tiles  ((c+k) mod32)
#define HID_STR 66    // float stride, hidden chunk

#define OFF_ALN (S*WIN_STR*4)                // 76048
#define OFF_SCR (OFF_ALN + S*ALN_STR*4)      // 114072
#define SMEM_BYTES (OFF_SCR + 32768)         // 146840 <= 160 KiB

__device__ __forceinline__ float bflo(unsigned u){ return __uint_as_float(u << 16); }
__device__ __forceinline__ float bfhi(unsigned u){ return __uint_as_float(u & 0xffff0000u); }
__device__ __forceinline__ unsigned f2bf(float x){            // RNE f32->bf16 (finite inputs)
  unsigned u = __float_as_uint(x);
  return (u + 0x7fffu + ((u >> 16) & 1u)) >> 16;
}

// LayerNorm of win -> packed bf16 pairs in aln. 8 lanes per row.
__device__ void ln_to_aln(const float* win, unsigned* aln,
                          const float* gw, const float* gb, int tid)
{
  int grp = tid >> 3, lj = tid & 7;
  if (grp < S) {
    const float* row = win + grp*WIN_STR;
    float sx = 0.f, sxx = 0.f;
    for (int c = lj; c < CH; c += 8) { float x = row[c]; sx += x; sxx += x*x; }
    #pragma unroll
    for (int d = 1; d < 8; d <<= 1) { sx += __shfl_xor(sx, d, 8); sxx += __shfl_xor(sxx, d, 8); }
    float mean = sx * (1.f/CH);
    float var  = sxx * (1.f/CH) - mean*mean;
    float rs = rsqrtf(var + 1e-5f);
    unsigned* arow = aln + grp*ALN_STR;
    for (int c2 = lj; c2 < CH/2; c2 += 8) {
      float x0 = (row[2*c2]   - mean)*rs*gw[2*c2]   + gb[2*c2];
      float x1 = (row[2*c2+1] - mean)*rs*gw[2*c2+1] + gb[2*c2+1];
      arow[c2] = f2bf(x0) | (f2bf(x1) << 16);
    }
  }
}

__global__ __launch_bounds__(NT)
void swin_kernel(const float* __restrict__ tokens,
                 const float* __restrict__ ipw,  const float* __restrict__ ipb,
                 const float* __restrict__ outw, const float* __restrict__ outb,
                 const float* __restrict__ ln1g, const float* __restrict__ ln1b,
                 const float* __restrict__ w1,   const float* __restrict__ b1,
                 const float* __restrict__ w2,   const float* __restrict__ b2,
                 const float* __restrict__ ln2g, const float* __restrict__ ln2b,
                 float* __restrict__ out)
{
  extern __shared__ char smem[];
  float*    win = (float*)smem;                     // [49][388] fp32 residual stream
  unsigned* aln = (unsigned*)(smem + OFF_ALN);      // [49][194] packed bf16 LN output
  char*     scr = smem + OFF_SCR;                   // 32 KB reusable scratch

  const int tid = threadIdx.x;
  const int wid = blockIdx.x;                       // 0..1023
  const int iw = wid & 7, ih = (wid >> 3) & 7, bt = wid >> 6;

  // ---------------- load window (coalesced float4) ----------------
  for (int idx = tid; idx < S*96; idx += NT) {
    int r = idx / 96, c4 = (idx % 96) * 4;
    int wi = r / 7, wj = r % 7;
    size_t g = ((size_t)bt*3136 + (size_t)(ih*7+wi)*56 + (iw*7+wj)) * CH + c4;
    *(float4*)&win[r*WIN_STR + c4] = *(const float4*)&tokens[g];
  }
  __syncthreads();

  // ---------------- LN1 ----------------
  ln_to_aln(win, aln, ln1g, ln1b, tid);
  __syncthreads();

  // ---------------- attention ----------------
  float* qh = (float*)scr;                // [49][37]
  float* kh = qh + S*QKV_STR;             // [49][37]
  float* vh = kh + S*QKV_STR;             // [49][37]
  float* Wq = vh + S*QKV_STR;             // [32][70]  staged in_proj tile
  float* sc = vh + S*QKV_STR;             // [49][56]  scores (aliases Wq, disjoint in time)
  float* oh = qh;                         // o_h reuses q region
  float* Wo = kh;                         // [64][33]  staged out_w tile (over dead k/v)

  for (int h = 0; h < NHD; ++h) {
    // (a) q, k, v for this head: [49][32] = aln @ Wslice^T
    {
      const int col = tid & 31, sgrp = tid >> 5;   // 16 row-groups, rows s = sgrp+16i
      for (int part = 0; part < 3; ++part) {
        float* dst = (part == 0) ? qh : (part == 1) ? kh : vh;
        const float* Wsrc = ipw + ((size_t)part*CH + h*HDM) * CH;
        float acc[4] = {0.f, 0.f, 0.f, 0.f};
        for (int kt = 0; kt < 6; ++kt) {
          { // stage Wq[32][64] (one float4 per thread, coalesced)
            int row = tid >> 4, c4 = (tid & 15) * 4;
            float4 wv = *(const float4*)&Wsrc[(size_t)row*CH + kt*64 + c4];
            float* d = &Wq[row*WQ_STR + c4];
            d[0]=wv.x; d[1]=wv.y; d[2]=wv.z; d[3]=wv.w;
          }
          __syncthreads();
          for (int k4 = 0; k4 < 16; ++k4) {
            float2 wA = *(float2*)&Wq[col*WQ_STR + 4*k4];
            float2 wB = *(float2*)&Wq[col*WQ_STR + 4*k4 + 2];
            #pragma unroll
            for (int i = 0; i < 4; ++i) {
              int s = sgrp + 16*i;
              if (s < S) {
                uint2 p = *(uint2*)&aln[s*ALN_STR + kt*32 + 2*k4];
                acc[i] += bflo(p.x)*wA.x + bfhi(p.x)*wA.y
                        + bflo(p.y)*wB.x + bfhi(p.y)*wB.y;
              }
            }
          }
          __syncthreads();
        }
        float bias = ipb[part*CH + h*HDM + col];
        float scl  = (part == 0) ? 0.17677669529663687f : 1.f;  // 1/sqrt(32) folded into q
        #pragma unroll
        for (int i = 0; i < 4; ++i) {
          int s = sgrp + 16*i;
          if (s < S) dst[s*QKV_STR + col] = (acc[i] + bias) * scl;
        }
        __syncthreads();
      }
    }

    // (b) scores = q k^T, softmax rows
    for (int idx = tid; idx < S*S; idx += NT) {
      int i = idx / S, j = idx - i*S;
      const float* qr = &qh[i*QKV_STR];
      const float* kr = &kh[j*QKV_STR];
      float sum = 0.f;
      #pragma unroll 8
      for (int k = 0; k < HDM; ++k) sum += qr[k]*kr[k];
      sc[i*SC_STR + j] = sum;
    }
    __syncthreads();
    {
      int grp = tid >> 3, lj = tid & 7;
      if (grp < S) {
        float* srow = &sc[grp*SC_STR];
        float mx = -1e30f;
        for (int j = lj; j < S; j += 8) mx = fmaxf(mx, srow[j]);
        #pragma unroll
        for (int d = 1; d < 8; d <<= 1) mx = fmaxf(mx, __shfl_xor(mx, d, 8));
        float sum = 0.f;
        for (int j = lj; j < S; j += 8) { float e = __expf(srow[j]-mx); srow[j]=e; sum+=e; }
        #pragma unroll
        for (int d = 1; d < 8; d <<= 1) sum += __shfl_xor(sum, d, 8);
        float inv = 1.f / sum;
        for (int j = lj; j < S; j += 8) srow[j] *= inv;
      }
    }
    __syncthreads();

    // (c) o_h = p @ v   -> oh (over dead q)
    {
      const int col = tid & 31, sgrp = tid >> 5;
      float acc[4] = {0.f, 0.f, 0.f, 0.f};
      for (int j = 0; j < S; ++j) {
        float vv = vh[j*QKV_STR + col];
        #pragma unroll
        for (int i = 0; i < 4; ++i) {
          int s = sgrp + 16*i;
          if (s < S) acc[i] += sc[s*SC_STR + j] * vv;
        }
      }
      #pragma unroll
      for (int i = 0; i < 4; ++i) {
        int s = sgrp + 16*i;
        if (s < S) oh[s*QKV_STR + col] = acc[i];
      }
    }
    __syncthreads();

    // (d) win += o_h @ out_w[:, h*32:+32]^T  (+ out_b once, at h==0)
    {
      const int col = tid & 63, sgrp = tid >> 6;
      for (int ob = 0; ob < 6; ++ob) {
        int o0 = ob * 64;
        { // stage Wo[64][32]
          int row = tid >> 3, c4 = (tid & 7) * 4;
          float4 wv = *(const float4*)&outw[(size_t)(o0+row)*CH + h*HDM + c4];
          float* d = &Wo[row*WO_STR + c4];
          d[0]=wv.x; d[1]=wv.y; d[2]=wv.z; d[3]=wv.w;
        }
        __syncthreads();
        #pragma unroll
        for (int i = 0; i < 7; ++i) {
          int s = sgrp + 8*i;
          if (s < S) {
            const float* orow = &oh[s*QKV_STR];
            const float* wrow = &Wo[col*WO_STR];
            float acc = 0.f;
            #pragma unroll 8
            for (int k = 0; k < HDM; ++k) acc += orow[k]*wrow[k];
            if (h == 0) acc += outb[o0+col];
            win[s*WIN_STR + o0 + col] += acc;
          }
        }
        __syncthreads();
      }
    }
  } // heads

  // ---------------- LN2 ----------------
  ln_to_aln(win, aln, ln2g, ln2b, tid);
  __syncthreads();

  // ---------------- MLP, fused over 64-wide hidden chunks ----------------
  {
    float* hidc = (float*)scr;              // [49][66]
    float* Wm   = hidc + S*HID_STR;         // [64][70]
    const int col = tid & 63, sgrp = tid >> 6;
    for (int cc = 0; cc < HIDN/64; ++cc) {
      int c0 = cc * 64;
      // (a) hidc = gelu(aln @ w1_chunk^T + b1)
      {
        float acc[7] = {0.f,0.f,0.f,0.f,0.f,0.f,0.f};
        for (int kt = 0; kt < 6; ++kt) {
          #pragma unroll
          for (int p = 0; p < 2; ++p) { // stage Wm[64][64]
            int idx = tid + p*NT;
            int row = idx >> 4, c4 = (idx & 15) * 4;
            float4 wv = *(const float4*)&w1[(size_t)(c0+row)*CH + kt*64 + c4];
            float* d = &Wm[row*WQ_STR + c4];
            d[0]=wv.x; d[1]=wv.y; d[2]=wv.z; d[3]=wv.w;
          }
          __syncthreads();
          for (int k4 = 0; k4 < 16; ++k4) {
            float2 wA = *(float2*)&Wm[col*WQ_STR + 4*k4];
            float2 wB = *(float2*)&Wm[col*WQ_STR + 4*k4 + 2];
            #pragma unroll
            for (int i = 0; i < 7; ++i) {
              int s = sgrp + 8*i;
              if (s < S) {
                uint2 pck = *(uint2*)&aln[s*ALN_STR + kt*32 + 2*k4];
                acc[i] += bflo(pck.x)*wA.x + bfhi(pck.x)*wA.y
                        + bflo(pck.y)*wB.x + bfhi(pck.y)*wB.y;
              }
            }
          }
          __syncthreads();
        }
        float bb = b1[c0 + col];
        #pragma unroll
        for (int i = 0; i < 7; ++i) {
          int s = sgrp + 8*i;
          if (s < S) {
            float x = acc[i] + bb;
            hidc[s*HID_STR + col] = 0.5f * x * (1.f + erff(x * 0.70710678118654752f));
          }
        }
        __syncthreads();
      }
      // (b) win += hidc @ w2_chunk^T  (+ b2 once, at cc==0)
      for (int ob = 0; ob < 6; ++ob) {
        int o0 = ob * 64;
        #pragma unroll
        for (int p = 0; p < 2; ++p) { // stage Wm[64][64] from w2
          int idx = tid + p*NT;
          int row = idx >> 4, c4 = (idx & 15) * 4;
          float4 wv = *(const float4*)&w2[(size_t)(o0+row)*HIDN + c0 + c4];
          float* d = &Wm[row*WQ_STR + c4];
          d[0]=wv.x; d[1]=wv.y; d[2]=wv.z; d[3]=wv.w;
        }
        __syncthreads();
        float acc[7] = {0.f,0.f,0.f,0.f,0.f,0.f,0.f};
        for (int k4 = 0; k4 < 16; ++k4) {
          float2 wA = *(float2*)&Wm[col*WQ_STR + 4*k4];
          float2 wB = *(float2*)&Wm[col*WQ_STR + 4*k4 + 2];
          #pragma unroll
          for (int i = 0; i < 7; ++i) {
            int s = sgrp + 8*i;
            if (s < S) {
              float2 h0 = *(float2*)&hidc[s*HID_STR + 4*k4];
              float2 h1 = *(float2*)&hidc[s*HID_STR + 4*k4 + 2];
              acc[i] += h0.x*wA.x + h0.y*wA.y + h1.x*wB.x + h1.y*wB.y;
            }
          }
        }
        #pragma unroll
        for (int i = 0; i < 7; ++i) {
          int s = sgrp + 8*i;
          if (s < S) {
            float add = acc[i] + (cc == 0 ? b2[o0+col] : 0.f);
            win[s*WIN_STR + o0 + col] += add;
          }
        }
        __syncthreads();
      }
    }
  }

  // ---------------- store ----------------
  for (int idx = tid; idx < S*96; idx += NT) {
    int r = idx / 96, c4 = (idx % 96) * 4;
    int wi = r / 7, wj = r % 7;
    size_t g = ((size_t)bt*3136 + (size_t)(ih*7+wi)*56 + (iw*7+wj)) * CH + c4;
    *(float4*)&out[g] = *(float4*)&win[r*WIN_STR + c4];
  }
}

extern "C" void kernel_launch(void* const* d_in, const int* in_sizes, int n_in,
                              void* d_out, int out_size, void* d_ws, size_t ws_size,
                              hipStream_t stream) {
  (void)in_sizes; (void)n_in; (void)d_ws; (void)ws_size; (void)out_size;
  const float* tokens = (const float*)d_in[0];
  const float* ipw  = (const float*)d_in[1];
  const float* ipb  = (const float*)d_in[2];
  const float* outw = (const float*)d_in[3];
  const float* outb = (const float*)d_in[4];
  const float* ln1g = (const float*)d_in[5];
  const float* ln1b = (const float*)d_in[6];
  const float* w1   = (const float*)d_in[7];
  const float* b1   = (const float*)d_in[8];
  const float* w2   = (const float*)d_in[9];
  const float* b2   = (const float*)d_in[10];
  const float* ln2g = (const float*)d_in[11];
  const float* ln2b = (const float*)d_in[12];
  float* out = (float*)d_out;

  (void)hipFuncSetAttribute((const void*)swin_kernel,
                            hipFuncAttributeMaxDynamicSharedMemorySize, SMEM_BYTES);
  hipLaunchKernelGGL(swin_kernel, dim3(1024), dim3(NT), SMEM_BYTES, stream,
                     tokens, ipw, ipb, outw, outb, ln1g, ln1b,
                     w1, b1, w2, b2, ln2g, ln2b, out);
}

// Round 2
// 640.444 us; speedup vs baseline: 23.7861x; 23.7861x over previous
//
#include <hip/hip_runtime.h>
#include <hip/hip_bf16.h>
#include <math.h>

using short8 = __attribute__((ext_vector_type(8))) short;
using f32x4  = __attribute__((ext_vector_type(4))) float;

#define MFMA_B16(A,B,C) __builtin_amdgcn_mfma_f32_16x16x32_bf16((A),(B),(C),0,0,0)

// ---------------- LDS layout (bytes) ----------------
#define ALN_OFF 0        // [49][392] u16  (stride 784B -> 16B aligned, 2-way banks)
#define ALN_STR 392
#define Q4_OFF  38464    // [49][136] u16
#define Q4_STR  136
#define K4_OFF  51840    // [49][136] u16
#define VT_OFF  65216    // [128][72] u16  (zero-initialized: token cols >=49 must be 0)
#define VT_STR  72
#define SC_OFF  83648    // [49][68] f32
#define SC_STR  68
#define P_OFF   97024    // [64][72] u16   (zero-initialized)
#define P_STR   72
#define OH_OFF  106240   // [49][40] u16
#define OH_STR  40
#define HID_OFF 110208   // [49][136] u16
#define HID_STR 136
#define SMEM_BYTES 131072 // incl. tail margin for harmless padded-row OOB reads

__device__ __forceinline__ unsigned f2bf(float x) {   // RNE f32->bf16
  unsigned u = __float_as_uint(x);
  return (u + 0x7fffu + ((u >> 16) & 1u)) >> 16;
}

template<bool BF>
__device__ __forceinline__ short8 loadB(const void* base, int row, int ldk, int k0) {
  if constexpr (BF) {
    return *(const short8*)((const unsigned short*)base + (size_t)row * ldk + k0);
  } else {
    const float* p = (const float*)base + (size_t)row * ldk + k0;
    float4 x = *(const float4*)p;
    float4 y = *(const float4*)(p + 4);
    short8 r;
    r[0]=(short)f2bf(x.x); r[1]=(short)f2bf(x.y); r[2]=(short)f2bf(x.z); r[3]=(short)f2bf(x.w);
    r[4]=(short)f2bf(y.x); r[5]=(short)f2bf(y.y); r[6]=(short)f2bf(y.z); r[7]=(short)f2bf(y.w);
    return r;
  }
}

__global__ void cvt_bf16(const float* __restrict__ src, unsigned short* __restrict__ dst, int n) {
  for (int i = blockIdx.x * blockDim.x + threadIdx.x; i < n; i += gridDim.x * blockDim.x)
    dst[i] = (unsigned short)f2bf(src[i]);
}

template<bool WBF>
__global__ __launch_bounds__(512, 2)
void swin_mfma(const float* __restrict__ tokens,
               const void* __restrict__ ipw,  const float* __restrict__ ipb,
               const void* __restrict__ outw, const float* __restrict__ outb,
               const float* __restrict__ ln1g, const float* __restrict__ ln1b,
               const void* __restrict__ w1,   const float* __restrict__ b1,
               const void* __restrict__ w2,   const float* __restrict__ b2,
               const float* __restrict__ ln2g, const float* __restrict__ ln2b,
               float* __restrict__ out)
{
  extern __shared__ char smem[];
  unsigned short* aln = (unsigned short*)(smem + ALN_OFF);
  unsigned short* q4  = (unsigned short*)(smem + Q4_OFF);
  unsigned short* k4  = (unsigned short*)(smem + K4_OFF);
  unsigned short* vT4 = (unsigned short*)(smem + VT_OFF);
  float*          sc  = (float*)         (smem + SC_OFF);
  unsigned short* P   = (unsigned short*)(smem + P_OFF);
  unsigned short* oh  = (unsigned short*)(smem + OH_OFF);
  unsigned short* hid = (unsigned short*)(smem + HID_OFF);

  const int tid = threadIdx.x;
  const int l  = tid & 63, wv = tid >> 6;
  const int cl = l & 15,  kg = l >> 4;
  const int wid = blockIdx.x;
  const int iw = wid & 7, ih = (wid >> 3) & 7, bt = wid >> 6;

  auto gidx = [&](int r, int c) -> size_t {
    int wi = r / 7, wj = r - wi * 7;
    return ((size_t)bt * 3136 + (size_t)((ih*7 + wi) * 56 + iw*7 + wj)) * 384 + c;
  };

  auto ln_pass = [&](const float* src, const float* gw, const float* gb) {
    int grp = tid >> 3, lj = tid & 7;
    if (grp < 49) {
      size_t base = gidx(grp, 0);
      float4 xv[12];
      float sx = 0.f, sxx = 0.f;
      #pragma unroll
      for (int k = 0; k < 12; ++k) {
        xv[k] = *(const float4*)&src[base + (lj + 8*k) * 4];
        sx  += xv[k].x + xv[k].y + xv[k].z + xv[k].w;
        sxx += xv[k].x*xv[k].x + xv[k].y*xv[k].y + xv[k].z*xv[k].z + xv[k].w*xv[k].w;
      }
      #pragma unroll
      for (int d = 1; d < 8; d <<= 1) { sx += __shfl_xor(sx, d, 8); sxx += __shfl_xor(sxx, d, 8); }
      float mean = sx * (1.f/384.f);
      float rs = rsqrtf(sxx * (1.f/384.f) - mean*mean + 1e-5f);
      unsigned short* arow = aln + grp * ALN_STR;
      #pragma unroll
      for (int k = 0; k < 12; ++k) {
        int c = (lj + 8*k) * 4;
        float4 gv = *(const float4*)&gw[c];
        float4 bv = *(const float4*)&gb[c];
        unsigned u0 = f2bf((xv[k].x-mean)*rs*gv.x + bv.x) | (f2bf((xv[k].y-mean)*rs*gv.y + bv.y) << 16);
        unsigned u1 = f2bf((xv[k].z-mean)*rs*gv.z + bv.z) | (f2bf((xv[k].w-mean)*rs*gv.w + bv.w) << 16);
        *(uint2*)&arow[c] = make_uint2(u0, u1);
      }
    }
  };

  // ---- init: LN1 + zero vT4 & P (K-side pads must be true zeros) ----
  for (int i = tid; i < (128*VT_STR*2)/4; i += 512) ((unsigned*)(smem + VT_OFF))[i] = 0u;
  for (int i = tid; i < (64*P_STR*2)/4;  i += 512) ((unsigned*)(smem + P_OFF))[i]  = 0u;
  ln_pass(tokens, ln1g, ln1b);
  __syncthreads();

  // ---- attention: 3 quads of 4 heads ----
  f32x4 opacc[3][4];
  #pragma unroll
  for (int a = 0; a < 3; ++a)
    #pragma unroll
    for (int b = 0; b < 4; ++b) opacc[a][b] = f32x4{0.f,0.f,0.f,0.f};

  for (int hg = 0; hg < 3; ++hg) {
    int h0 = hg * 4;
    // (a) QKV gemm for 4 heads: 24 col-tiles, 3 per wave, 4 row-tiles each
    #pragma unroll
    for (int cii = 0; cii < 3; ++cii) {
      int ci = wv * 3 + cii;
      int lf = ci * 16 + cl;
      int part = lf >> 7, wf = lf & 127;
      int grow = part * 384 + h0 * 32 + wf;
      f32x4 d0{0.f,0.f,0.f,0.f}, d1{0.f,0.f,0.f,0.f}, d2{0.f,0.f,0.f,0.f}, d3{0.f,0.f,0.f,0.f};
      for (int kt = 0; kt < 12; ++kt) {
        int k0 = kt * 32 + kg * 8;
        short8 bw = loadB<WBF>(ipw, grow, 384, k0);
        short8 a0 = *(const short8*)&aln[(cl     ) * ALN_STR + k0];
        short8 a1 = *(const short8*)&aln[(cl + 16) * ALN_STR + k0];
        short8 a2 = *(const short8*)&aln[(cl + 32) * ALN_STR + k0];
        short8 a3 = *(const short8*)&aln[(cl + 48) * ALN_STR + k0];
        d0 = MFMA_B16(a0, bw, d0);
        d1 = MFMA_B16(a1, bw, d1);
        d2 = MFMA_B16(a2, bw, d2);
        d3 = MFMA_B16(a3, bw, d3);
      }
      float bias = ipb[grow];
      float scl = (part == 0) ? 0.17677669529663687f : 1.f;  // fold 1/sqrt(32) into q
      #pragma unroll
      for (int ri = 0; ri < 4; ++ri) {
        f32x4 dd = (ri == 0) ? d0 : (ri == 1) ? d1 : (ri == 2) ? d2 : d3;
        #pragma unroll
        for (int rg = 0; rg < 4; ++rg) {
          int row = kg * 4 + rg + 16 * ri;
          if (row < 49) {
            unsigned short bv = (unsigned short)f2bf((dd[rg] + bias) * scl);
            if      (part == 0) q4[row * Q4_STR + wf] = bv;
            else if (part == 1) k4[row * Q4_STR + wf] = bv;
            else                vT4[wf * VT_STR + row] = bv;
          }
        }
      }
    }
    __syncthreads();

    // (b) per head in quad
    for (int hl = 0; hl < 4; ++hl) {
      int hh = h0 + hl;
      // scores: 16 tiles, 2 per wave, K=32
      #pragma unroll
      for (int tt = 0; tt < 2; ++tt) {
        int t = wv * 2 + tt, ri = t & 3, ci = t >> 2;
        short8 aq = *(const short8*)&q4[(cl + 16*ri) * Q4_STR + hl*32 + kg*8];
        short8 bk = *(const short8*)&k4[(cl + 16*ci) * Q4_STR + hl*32 + kg*8];
        f32x4 d{0.f,0.f,0.f,0.f};
        d = MFMA_B16(aq, bk, d);
        #pragma unroll
        for (int rg = 0; rg < 4; ++rg) {
          int row = kg * 4 + rg + 16 * ri;
          if (row < 49) sc[row * SC_STR + ci*16 + cl] = d[rg];
        }
      }
      __syncthreads();
      // softmax rows -> P (bf16), cols >=49 zeroed
      {
        int grp = tid >> 3, lj = tid & 7;
        if (grp < 49) {
          float vals[7]; float mx = -1e30f;
          #pragma unroll
          for (int k = 0; k < 7; ++k) {
            int j = lj + 8*k;
            float v = (j < 49) ? sc[grp * SC_STR + j] : -1e30f;
            vals[k] = v; mx = fmaxf(mx, v);
          }
          #pragma unroll
          for (int d = 1; d < 8; d <<= 1) mx = fmaxf(mx, __shfl_xor(mx, d, 8));
          float sum = 0.f;
          #pragma unroll
          for (int k = 0; k < 7; ++k) { float e = __expf(vals[k] - mx); vals[k] = e; sum += e; }
          #pragma unroll
          for (int d = 1; d < 8; d <<= 1) sum += __shfl_xor(sum, d, 8);
          float inv = 1.f / sum;
          unsigned short* prow = &P[grp * P_STR];
          #pragma unroll
          for (int k = 0; k < 8; ++k) {
            int j = lj + 8*k;
            float pv = (k < 7) ? vals[k] * inv : 0.f;
            if (j >= 49) pv = 0.f;
            prow[j] = (unsigned short)f2bf(pv);
          }
        }
      }
      __syncthreads();
      // PV: 8 tiles, 1 per wave, K=64
      {
        int ri = wv & 3, ci = wv >> 2;
        f32x4 d{0.f,0.f,0.f,0.f};
        #pragma unroll
        for (int kt = 0; kt < 2; ++kt) {
          short8 ap = *(const short8*)&P[(cl + 16*ri) * P_STR + kt*32 + kg*8];
          short8 bv = *(const short8*)&vT4[(hl*32 + ci*16 + cl) * VT_STR + kt*32 + kg*8];
          d = MFMA_B16(ap, bv, d);
        }
        #pragma unroll
        for (int rg = 0; rg < 4; ++rg) {
          int row = kg * 4 + rg + 16 * ri;
          if (row < 49) oh[row * OH_STR + ci*16 + cl] = (unsigned short)f2bf(d[rg]);
        }
      }
      __syncthreads();
      // out-proj partial for this head: 12 tiles/wave, K=32
      {
        short8 ao0 = *(const short8*)&oh[(cl     ) * OH_STR + kg*8];
        short8 ao1 = *(const short8*)&oh[(cl + 16) * OH_STR + kg*8];
        short8 ao2 = *(const short8*)&oh[(cl + 32) * OH_STR + kg*8];
        short8 ao3 = *(const short8*)&oh[(cl + 48) * OH_STR + kg*8];
        #pragma unroll
        for (int cii = 0; cii < 3; ++cii) {
          int n = (wv*3 + cii) * 16 + cl;
          short8 bw = loadB<WBF>(outw, n, 384, hh*32 + kg*8);
          opacc[cii][0] = MFMA_B16(ao0, bw, opacc[cii][0]);
          opacc[cii][1] = MFMA_B16(ao1, bw, opacc[cii][1]);
          opacc[cii][2] = MFMA_B16(ao2, bw, opacc[cii][2]);
          opacc[cii][3] = MFMA_B16(ao3, bw, opacc[cii][3]);
        }
      }
      // no barrier needed: next phase's LDS writes are >=1 barrier away
    }
  }

  // ---- win = tokens + attn_out + out_b  -> d_out (fp32 residual in global) ----
  #pragma unroll
  for (int cii = 0; cii < 3; ++cii) {
    int col = (wv*3 + cii) * 16 + cl;
    float ob = outb[col];
    #pragma unroll
    for (int ri = 0; ri < 4; ++ri) {
      #pragma unroll
      for (int rg = 0; rg < 4; ++rg) {
        int row = kg*4 + rg + 16*ri;
        if (row < 49) {
          size_t g = gidx(row, col);
          out[g] = tokens[g] + opacc[cii][ri][rg] + ob;
        }
      }
    }
  }
  __syncthreads();                 // drains vmcnt; win visible via L2 (same CU)

  // ---- LN2 ----
  ln_pass(out, ln2g, ln2b);
  __syncthreads();

  // ---- MLP: 12 chunks of 128 hidden; MLP2 accumulates in registers ----
  f32x4 macc[3][4];
  #pragma unroll
  for (int a = 0; a < 3; ++a)
    #pragma unroll
    for (int b = 0; b < 4; ++b) macc[a][b] = f32x4{0.f,0.f,0.f,0.f};

  for (int cc = 0; cc < 12; ++cc) {
    int c0 = cc * 128;
    // MLP1: each wave owns 16 hidden cols (1 col-tile), 4 row-tiles
    {
      int n = c0 + wv*16 + cl;
      f32x4 e0{0.f,0.f,0.f,0.f}, e1{0.f,0.f,0.f,0.f}, e2{0.f,0.f,0.f,0.f}, e3{0.f,0.f,0.f,0.f};
      for (int kt = 0; kt < 12; ++kt) {
        int k0 = kt*32 + kg*8;
        short8 bw = loadB<WBF>(w1, n, 384, k0);
        short8 a0 = *(const short8*)&aln[(cl     ) * ALN_STR + k0];
        short8 a1 = *(const short8*)&aln[(cl + 16) * ALN_STR + k0];
        short8 a2 = *(const short8*)&aln[(cl + 32) * ALN_STR + k0];
        short8 a3 = *(const short8*)&aln[(cl + 48) * ALN_STR + k0];
        e0 = MFMA_B16(a0, bw, e0);
        e1 = MFMA_B16(a1, bw, e1);
        e2 = MFMA_B16(a2, bw, e2);
        e3 = MFMA_B16(a3, bw, e3);
      }
      float bb = b1[n];
      #pragma unroll
      for (int ri = 0; ri < 4; ++ri) {
        f32x4 ee = (ri == 0) ? e0 : (ri == 1) ? e1 : (ri == 2) ? e2 : e3;
        #pragma unroll
        for (int rg = 0; rg < 4; ++rg) {
          int row = kg*4 + rg + 16*ri;
          if (row < 49) {
            float x = ee[rg] + bb;
            float gl = 0.5f * x * (1.f + erff(x * 0.70710678118654752f));
            hid[row * HID_STR + wv*16 + cl] = (unsigned short)f2bf(gl);
          }
        }
      }
    }
    __syncthreads();
    // MLP2 partial: 12 tiles/wave, K=128 (4 mfma)
    #pragma unroll
    for (int kt = 0; kt < 4; ++kt) {
      int k0 = kt*32 + kg*8;
      short8 h0_ = *(const short8*)&hid[(cl     ) * HID_STR + k0];
      short8 h1_ = *(const short8*)&hid[(cl + 16) * HID_STR + k0];
      short8 h2_ = *(const short8*)&hid[(cl + 32) * HID_STR + k0];
      short8 h3_ = *(const short8*)&hid[(cl + 48) * HID_STR + k0];
      #pragma unroll
      for (int cii = 0; cii < 3; ++cii) {
        int n = (wv*3 + cii) * 16 + cl;
        short8 bw = loadB<WBF>(w2, n, 1536, c0 + k0);
        macc[cii][0] = MFMA_B16(h0_, bw, macc[cii][0]);
        macc[cii][1] = MFMA_B16(h1_, bw, macc[cii][1]);
        macc[cii][2] = MFMA_B16(h2_, bw, macc[cii][2]);
        macc[cii][3] = MFMA_B16(h3_, bw, macc[cii][3]);
      }
    }
    __syncthreads();
  }

  // ---- final: out = win + mlp + b2 ----
  #pragma unroll
  for (int cii = 0; cii < 3; ++cii) {
    int col = (wv*3 + cii) * 16 + cl;
    float bb2 = b2[col];
    #pragma unroll
    for (int ri = 0; ri < 4; ++ri) {
      #pragma unroll
      for (int rg = 0; rg < 4; ++rg) {
        int row = kg*4 + rg + 16*ri;
        if (row < 49) {
          size_t g = gidx(row, col);
          out[g] = out[g] + macc[cii][ri][rg] + bb2;
        }
      }
    }
  }
}

// ws layout (bf16 elements): ipw[442368] | outw[147456] | w1[589824] | w2[589824]
#define WS_IPW  0
#define WS_OUTW 442368
#define WS_W1   589824
#define WS_W2   1179648
#define WS_TOT  1769472

extern "C" void kernel_launch(void* const* d_in, const int* in_sizes, int n_in,
                              void* d_out, int out_size, void* d_ws, size_t ws_size,
                              hipStream_t stream) {
  (void)in_sizes; (void)n_in; (void)out_size;
  const float* tokens = (const float*)d_in[0];
  const float* ipw  = (const float*)d_in[1];
  const float* ipb  = (const float*)d_in[2];
  const float* outw = (const float*)d_in[3];
  const float* outb = (const float*)d_in[4];
  const float* ln1g = (const float*)d_in[5];
  const float* ln1b = (const float*)d_in[6];
  const float* w1   = (const float*)d_in[7];
  const float* b1   = (const float*)d_in[8];
  const float* w2   = (const float*)d_in[9];
  const float* b2   = (const float*)d_in[10];
  const float* ln2g = (const float*)d_in[11];
  const float* ln2b = (const float*)d_in[12];
  float* out = (float*)d_out;

  bool wbf = (ws_size >= (size_t)WS_TOT * 2);
  if (wbf) {
    unsigned short* wsp = (unsigned short*)d_ws;
    hipLaunchKernelGGL(cvt_bf16, dim3(512), dim3(256), 0, stream, ipw,  wsp + WS_IPW,  442368);
    hipLaunchKernelGGL(cvt_bf16, dim3(512), dim3(256), 0, stream, outw, wsp + WS_OUTW, 147456);
    hipLaunchKernelGGL(cvt_bf16, dim3(512), dim3(256), 0, stream, w1,   wsp + WS_W1,   589824);
    hipLaunchKernelGGL(cvt_bf16, dim3(512), dim3(256), 0, stream, w2,   wsp + WS_W2,   589824);
    (void)hipFuncSetAttribute((const void*)swin_mfma<true>,
                              hipFuncAttributeMaxDynamicSharedMemorySize, SMEM_BYTES);
    hipLaunchKernelGGL((swin_mfma<true>), dim3(1024), dim3(512), SMEM_BYTES, stream,
                       tokens, (const void*)(wsp + WS_IPW), ipb,
                       (const void*)(wsp + WS_OUTW), outb, ln1g, ln1b,
                       (const void*)(wsp + WS_W1), b1, (const void*)(wsp + WS_W2), b2,
                       ln2g, ln2b, out);
  } else {
    (void)hipFuncSetAttribute((const void*)swin_mfma<false>,
                              hipFuncAttributeMaxDynamicSharedMemorySize, SMEM_BYTES);
    hipLaunchKernelGGL((swin_mfma<false>), dim3(1024), dim3(512), SMEM_BYTES, stream,
                       tokens, (const void*)ipw, ipb, (const void*)outw, outb, ln1g, ln1b,
                       (const void*)w1, b1, (const void*)w2, b2, ln2g, ln2b, out);
  }
}

// Round 3
// 499.575 us; speedup vs baseline: 30.4933x; 1.2820x over previous
//
#include <hip/hip_runtime.h>
#include <hip/hip_bf16.h>
#include <math.h>

using short8 = __attribute__((ext_vector_type(8))) short;
using f32x4  = __attribute__((ext_vector_type(4))) float;

#define MFMA_B16(A,B,C) __builtin_amdgcn_mfma_f32_16x16x32_bf16((A),(B),(C),0,0,0)

// ---------------- LDS layout (bytes) ----------------
// aln [49][392]u16 (reads spill harmlessly into pool: garbage rows 49..63 only
// feed discarded C rows). Pool: q2/k2 [49][72], vT2 [64][72] (zero-init, cols
// >=49 stay 0), sc16 [49][68]u16, P [49][72] (+spill), oh [49][40] (+spill).
// hid [49][136] aliases q2.. during MLP. Total 79 KiB -> 2 blocks/CU.
#define ALN_STR 392
#define Q2_OFF  38416
#define QK_STR  72
#define K2_OFF  45472
#define VT_OFF  52528
#define VT_STR  72
#define SC_OFF  61744
#define SC_STR  68
#define P_OFF   68408
#define P_STR   72
#define OH_OFF  75464
#define OH_STR  40
#define HID_OFF 38416
#define HID_STR 136
#define SMEM_BYTES 80896   // 79 KiB

__device__ __forceinline__ unsigned f2bf(float x) {   // RNE f32->bf16
  unsigned u = __float_as_uint(x);
  return (u + 0x7fffu + ((u >> 16) & 1u)) >> 16;
}
__device__ __forceinline__ float bf2f(unsigned short b) {
  return __uint_as_float(((unsigned)b) << 16);
}

// B-operand load. WBF: packed fragment layout [tile][kchunk][lane][8] bf16 ->
// one coalesced 16B/lane read. !WBF: gather from f32 row-major + convert.
template<bool WBF>
__device__ __forceinline__ short8 loadW(const void* base, int tile, int K8, int kcb,
                                        int l, int row, int ldk, int k0) {
  if constexpr (WBF) {
    return *(const short8*)((const unsigned short*)base +
                            (((size_t)(tile * K8 + kcb)) << 7) + l * 8);
  } else {
    const float* p = (const float*)base + (size_t)row * ldk + k0;
    float4 x = *(const float4*)p;
    float4 y = *(const float4*)(p + 4);
    short8 r;
    r[0]=(short)f2bf(x.x); r[1]=(short)f2bf(x.y); r[2]=(short)f2bf(x.z); r[3]=(short)f2bf(x.w);
    r[4]=(short)f2bf(y.x); r[5]=(short)f2bf(y.y); r[6]=(short)f2bf(y.z); r[7]=(short)f2bf(y.w);
    return r;
  }
}

// Repack f32 [rows][K] -> bf16 fragment order [tile][kc][r16][8].
__global__ void cvt_pack(const float* __restrict__ src, unsigned short* __restrict__ dst,
                         int K, int n) {
  int K8 = K >> 3;
  int i = blockIdx.x * blockDim.x + threadIdx.x;
  if (i >= n) return;
  int e = i & 7;
  int idx = i >> 3;
  int r = idx & 15; idx >>= 4;
  int kc = idx % K8, ci = idx / K8;
  dst[i] = (unsigned short)f2bf(src[(size_t)(ci * 16 + r) * K + kc * 8 + e]);
}

template<bool WBF>
__global__ __launch_bounds__(512, 4)
void swin_mfma(const float* __restrict__ tokens,
               const void* __restrict__ ipw,  const float* __restrict__ ipb,
               const void* __restrict__ outw, const float* __restrict__ outb,
               const float* __restrict__ ln1g, const float* __restrict__ ln1b,
               const void* __restrict__ w1,   const float* __restrict__ b1,
               const void* __restrict__ w2,   const float* __restrict__ b2,
               const float* __restrict__ ln2g, const float* __restrict__ ln2b,
               float* __restrict__ out)
{
  extern __shared__ char smem[];
  unsigned short* aln = (unsigned short*)smem;
  unsigned short* q2  = (unsigned short*)(smem + Q2_OFF);
  unsigned short* k2  = (unsigned short*)(smem + K2_OFF);
  unsigned short* vT2 = (unsigned short*)(smem + VT_OFF);
  unsigned short* sc16= (unsigned short*)(smem + SC_OFF);
  unsigned short* P   = (unsigned short*)(smem + P_OFF);
  unsigned short* oh  = (unsigned short*)(smem + OH_OFF);
  unsigned short* hid = (unsigned short*)(smem + HID_OFF);

  const int tid = threadIdx.x;
  const int l  = tid & 63, wv = tid >> 6;
  const int cl = l & 15,  kg = l >> 4;
  const int wid = blockIdx.x;
  const int iw = wid & 7, ih = (wid >> 3) & 7, bt = wid >> 6;

  auto gidx = [&](int r, int c) -> size_t {
    int wi = r / 7, wj = r - wi * 7;
    return ((size_t)bt * 3136 + (size_t)((ih*7 + wi) * 56 + iw*7 + wj)) * 384 + c;
  };

  auto ln_pass = [&](const float* src, const float* gw, const float* gb) {
    int grp = tid >> 3, lj = tid & 7;
    if (grp < 49) {
      size_t base = gidx(grp, 0);
      float4 xv[12];
      float sx = 0.f, sxx = 0.f;
      #pragma unroll
      for (int k = 0; k < 12; ++k) {
        xv[k] = *(const float4*)&src[base + (lj + 8*k) * 4];
        sx  += xv[k].x + xv[k].y + xv[k].z + xv[k].w;
        sxx += xv[k].x*xv[k].x + xv[k].y*xv[k].y + xv[k].z*xv[k].z + xv[k].w*xv[k].w;
      }
      #pragma unroll
      for (int d = 1; d < 8; d <<= 1) { sx += __shfl_xor(sx, d, 8); sxx += __shfl_xor(sxx, d, 8); }
      float mean = sx * (1.f/384.f);
      float rs = rsqrtf(sxx * (1.f/384.f) - mean*mean + 1e-5f);
      unsigned short* arow = aln + grp * ALN_STR;
      #pragma unroll
      for (int k = 0; k < 12; ++k) {
        int c = (lj + 8*k) * 4;
        float4 gv = *(const float4*)&gw[c];
        float4 bv = *(const float4*)&gb[c];
        unsigned u0 = f2bf((xv[k].x-mean)*rs*gv.x + bv.x) | (f2bf((xv[k].y-mean)*rs*gv.y + bv.y) << 16);
        unsigned u1 = f2bf((xv[k].z-mean)*rs*gv.z + bv.z) | (f2bf((xv[k].w-mean)*rs*gv.w + bv.w) << 16);
        *(uint2*)&arow[c] = make_uint2(u0, u1);
      }
    }
  };

  // ---- init: zero vT2+P pads, LN1 ----
  for (int i = tid; i < (64*VT_STR)/2; i += 512) ((unsigned*)(smem + VT_OFF))[i] = 0u;
  for (int i = tid; i < (49*P_STR)/2;  i += 512) ((unsigned*)(smem + P_OFF))[i]  = 0u;
  ln_pass(tokens, ln1g, ln1b);
  __syncthreads();

  f32x4 opacc[3][4];
  #pragma unroll
  for (int a = 0; a < 3; ++a)
    #pragma unroll
    for (int b = 0; b < 4; ++b) opacc[a][b] = f32x4{0.f,0.f,0.f,0.f};

  const int ri0 = wv & 3, chalf = wv >> 2;   // QKV: fixed row-tile per wave
  const int arow0 = (cl + 16 * ri0) * ALN_STR;

  for (int pr = 0; pr < 6; ++pr) {
    // ---- QKV for head pair (2pr, 2pr+1): cols [64q|64k|64v], 12 col-tiles.
    // Wave handles ri=ri0, ci = chalf + 2j (j=0..5), in two halves of 3.
    #pragma unroll
    for (int half = 0; half < 2; ++half) {
      int cia[3], tilea[3], growa[3];
      #pragma unroll
      for (int j = 0; j < 3; ++j) {
        int ci = chalf + 2 * (half * 3 + j);
        int part = ci >> 2, wt = ci & 3;
        cia[j] = ci;
        tilea[j] = part * 24 + pr * 4 + wt;
        growa[j] = part * 384 + pr * 64 + wt * 16 + cl;
      }
      f32x4 d0{0,0,0,0}, d1{0,0,0,0}, d2{0,0,0,0};
      #pragma unroll
      for (int kt = 0; kt < 12; ++kt) {
        int k0 = kt * 32 + kg * 8;
        short8 a = *(const short8*)&aln[arow0 + k0];
        short8 b0 = loadW<WBF>(ipw, tilea[0], 48, kt*4, l, growa[0], 384, k0);
        short8 b1 = loadW<WBF>(ipw, tilea[1], 48, kt*4, l, growa[1], 384, k0);
        short8 b2 = loadW<WBF>(ipw, tilea[2], 48, kt*4, l, growa[2], 384, k0);
        d0 = MFMA_B16(a, b0, d0);
        d1 = MFMA_B16(a, b1, d1);
        d2 = MFMA_B16(a, b2, d2);
      }
      #pragma unroll
      for (int j = 0; j < 3; ++j) {
        f32x4 dd = (j == 0) ? d0 : (j == 1) ? d1 : d2;
        int part = cia[j] >> 2;
        int within = (cia[j] & 3) * 16 + cl;
        float bias = ipb[growa[j]];
        float scl = (part == 0) ? 0.17677669529663687f : 1.f;
        #pragma unroll
        for (int rg = 0; rg < 4; ++rg) {
          int row = kg * 4 + rg + 16 * ri0;
          if (row < 49) {
            unsigned short bv = (unsigned short)f2bf((dd[rg] + bias) * scl);
            if      (part == 0) q2[row * QK_STR + within] = bv;
            else if (part == 1) k2[row * QK_STR + within] = bv;
            else                vT2[within * VT_STR + row] = bv;
          }
        }
      }
    }
    __syncthreads();

    for (int hl = 0; hl < 2; ++hl) {
      int hh = 2 * pr + hl;
      // prefetch out-proj B tiles (land during scores/softmax/PV)
      short8 Bo0 = loadW<WBF>(outw, wv*3+0, 48, hh*4, l, (wv*3+0)*16+cl, 384, hh*32 + kg*8);
      short8 Bo1 = loadW<WBF>(outw, wv*3+1, 48, hh*4, l, (wv*3+1)*16+cl, 384, hh*32 + kg*8);
      short8 Bo2 = loadW<WBF>(outw, wv*3+2, 48, hh*4, l, (wv*3+2)*16+cl, 384, hh*32 + kg*8);

      // scores: 16 tiles, 2/wave, K=32
      #pragma unroll
      for (int tt = 0; tt < 2; ++tt) {
        int t = wv * 2 + tt, ri = t & 3, ci = t >> 2;
        short8 aq = *(const short8*)&q2[(cl + 16*ri) * QK_STR + hl*32 + kg*8];
        short8 bk = *(const short8*)&k2[(cl + 16*ci) * QK_STR + hl*32 + kg*8];
        f32x4 d{0,0,0,0};
        d = MFMA_B16(aq, bk, d);
        #pragma unroll
        for (int rg = 0; rg < 4; ++rg) {
          int row = kg * 4 + rg + 16 * ri;
          if (row < 49) sc16[row * SC_STR + ci*16 + cl] = (unsigned short)f2bf(d[rg]);
        }
      }
      __syncthreads();
      // softmax -> P (cols >=49 zero)
      {
        int grp = tid >> 3, lj = tid & 7;
        if (grp < 49) {
          float vals[7]; float mx = -1e30f;
          #pragma unroll
          for (int k = 0; k < 7; ++k) {
            int j = lj + 8*k;
            float v = (j < 49) ? bf2f(sc16[grp * SC_STR + j]) : -1e30f;
            vals[k] = v; mx = fmaxf(mx, v);
          }
          #pragma unroll
          for (int d = 1; d < 8; d <<= 1) mx = fmaxf(mx, __shfl_xor(mx, d, 8));
          float sum = 0.f;
          #pragma unroll
          for (int k = 0; k < 7; ++k) { float e = __expf(vals[k] - mx); vals[k] = e; sum += e; }
          #pragma unroll
          for (int d = 1; d < 8; d <<= 1) sum += __shfl_xor(sum, d, 8);
          float inv = 1.f / sum;
          unsigned short* prow = &P[grp * P_STR];
          #pragma unroll
          for (int k = 0; k < 8; ++k) {
            int j = lj + 8*k;
            float pv = (k < 7 && j < 49) ? vals[k] * inv : 0.f;
            prow[j] = (unsigned short)f2bf(pv);
          }
        }
      }
      __syncthreads();
      // PV: 8 tiles, 1/wave, K=64
      {
        int ri = wv & 3, ci = wv >> 2;
        f32x4 d{0,0,0,0};
        #pragma unroll
        for (int kt = 0; kt < 2; ++kt) {
          short8 ap = *(const short8*)&P[(cl + 16*ri) * P_STR + kt*32 + kg*8];
          short8 bv = *(const short8*)&vT2[(hl*32 + ci*16 + cl) * VT_STR + kt*32 + kg*8];
          d = MFMA_B16(ap, bv, d);
        }
        #pragma unroll
        for (int rg = 0; rg < 4; ++rg) {
          int row = kg * 4 + rg + 16 * ri;
          if (row < 49) oh[row * OH_STR + ci*16 + cl] = (unsigned short)f2bf(d[rg]);
        }
      }
      __syncthreads();
      // out-proj partial (prefetched B)
      {
        short8 ao0 = *(const short8*)&oh[(cl     ) * OH_STR + kg*8];
        short8 ao1 = *(const short8*)&oh[(cl + 16) * OH_STR + kg*8];
        short8 ao2 = *(const short8*)&oh[(cl + 32) * OH_STR + kg*8];
        short8 ao3 = *(const short8*)&oh[(cl + 48) * OH_STR + kg*8];
        opacc[0][0] = MFMA_B16(ao0, Bo0, opacc[0][0]);
        opacc[0][1] = MFMA_B16(ao1, Bo0, opacc[0][1]);
        opacc[0][2] = MFMA_B16(ao2, Bo0, opacc[0][2]);
        opacc[0][3] = MFMA_B16(ao3, Bo0, opacc[0][3]);
        opacc[1][0] = MFMA_B16(ao0, Bo1, opacc[1][0]);
        opacc[1][1] = MFMA_B16(ao1, Bo1, opacc[1][1]);
        opacc[1][2] = MFMA_B16(ao2, Bo1, opacc[1][2]);
        opacc[1][3] = MFMA_B16(ao3, Bo1, opacc[1][3]);
        opacc[2][0] = MFMA_B16(ao0, Bo2, opacc[2][0]);
        opacc[2][1] = MFMA_B16(ao1, Bo2, opacc[2][1]);
        opacc[2][2] = MFMA_B16(ao2, Bo2, opacc[2][2]);
        opacc[2][3] = MFMA_B16(ao3, Bo2, opacc[2][3]);
      }
      // safe without barrier: next writes to oh are 2 barriers away
    }
  }

  // ---- win = tokens + attn + out_b -> out ----
  #pragma unroll
  for (int cii = 0; cii < 3; ++cii) {
    int col = (wv*3 + cii) * 16 + cl;
    float ob = outb[col];
    #pragma unroll
    for (int ri = 0; ri < 4; ++ri) {
      #pragma unroll
      for (int rg = 0; rg < 4; ++rg) {
        int row = kg*4 + rg + 16*ri;
        if (row < 49) {
          size_t g = gidx(row, col);
          out[g] = tokens[g] + opacc[cii][ri][rg] + ob;
        }
      }
    }
  }
  __syncthreads();

  // ---- LN2 ----
  ln_pass(out, ln2g, ln2b);
  __syncthreads();

  // ---- MLP ----
  f32x4 macc[3][4];
  #pragma unroll
  for (int a = 0; a < 3; ++a)
    #pragma unroll
    for (int b = 0; b < 4; ++b) macc[a][b] = f32x4{0.f,0.f,0.f,0.f};

  for (int cc = 0; cc < 12; ++cc) {
    // MLP1: wave owns 16 hidden cols
    {
      int tile = cc * 8 + wv;
      int n = cc * 128 + wv * 16 + cl;
      f32x4 e0{0,0,0,0}, e1{0,0,0,0}, e2{0,0,0,0}, e3{0,0,0,0};
      #pragma unroll
      for (int kt = 0; kt < 12; ++kt) {
        int k0 = kt * 32 + kg * 8;
        short8 bw = loadW<WBF>(w1, tile, 48, kt*4, l, n, 384, k0);
        short8 a0 = *(const short8*)&aln[(cl     ) * ALN_STR + k0];
        short8 a1 = *(const short8*)&aln[(cl + 16) * ALN_STR + k0];
        short8 a2 = *(const short8*)&aln[(cl + 32) * ALN_STR + k0];
        short8 a3 = *(const short8*)&aln[(cl + 48) * ALN_STR + k0];
        e0 = MFMA_B16(a0, bw, e0);
        e1 = MFMA_B16(a1, bw, e1);
        e2 = MFMA_B16(a2, bw, e2);
        e3 = MFMA_B16(a3, bw, e3);
      }
      float bb = b1[n];
      #pragma unroll
      for (int ri = 0; ri < 4; ++ri) {
        f32x4 ee = (ri == 0) ? e0 : (ri == 1) ? e1 : (ri == 2) ? e2 : e3;
        #pragma unroll
        for (int rg = 0; rg < 4; ++rg) {
          int row = kg*4 + rg + 16*ri;
          if (row < 49) {
            float x = ee[rg] + bb;
            float gl = 0.5f * x * (1.f + erff(x * 0.70710678118654752f));
            hid[row * HID_STR + wv*16 + cl] = (unsigned short)f2bf(gl);
          }
        }
      }
    }
    __syncthreads();
    // MLP2 partial: K=128
    #pragma unroll
    for (int kt = 0; kt < 4; ++kt) {
      int k0 = kt * 32 + kg * 8;
      short8 h0_ = *(const short8*)&hid[(cl     ) * HID_STR + k0];
      short8 h1_ = *(const short8*)&hid[(cl + 16) * HID_STR + k0];
      short8 h2_ = *(const short8*)&hid[(cl + 32) * HID_STR + k0];
      short8 h3_ = *(const short8*)&hid[(cl + 48) * HID_STR + k0];
      #pragma unroll
      for (int cii = 0; cii < 3; ++cii) {
        short8 bw = loadW<WBF>(w2, wv*3+cii, 192, cc*16 + kt*4, l,
                               (wv*3+cii)*16+cl, 1536, cc*128 + k0);
        macc[cii][0] = MFMA_B16(h0_, bw, macc[cii][0]);
        macc[cii][1] = MFMA_B16(h1_, bw, macc[cii][1]);
        macc[cii][2] = MFMA_B16(h2_, bw, macc[cii][2]);
        macc[cii][3] = MFMA_B16(h3_, bw, macc[cii][3]);
      }
    }
    __syncthreads();
  }

  // ---- final: out += mlp + b2 ----
  #pragma unroll
  for (int cii = 0; cii < 3; ++cii) {
    int col = (wv*3 + cii) * 16 + cl;
    float bb2 = b2[col];
    #pragma unroll
    for (int ri = 0; ri < 4; ++ri) {
      #pragma unroll
      for (int rg = 0; rg < 4; ++rg) {
        int row = kg*4 + rg + 16*ri;
        if (row < 49) {
          size_t g = gidx(row, col);
          out[g] = out[g] + macc[cii][ri][rg] + bb2;
        }
      }
    }
  }
}

// ws layout (bf16 elements): ipw[442368] | outw[147456] | w1[589824] | w2[589824]
#define WS_IPW  0
#define WS_OUTW 442368
#define WS_W1   589824
#define WS_W2   1179648
#define WS_TOT  1769472

extern "C" void kernel_launch(void* const* d_in, const int* in_sizes, int n_in,
                              void* d_out, int out_size, void* d_ws, size_t ws_size,
                              hipStream_t stream) {
  (void)in_sizes; (void)n_in; (void)out_size;
  const float* tokens = (const float*)d_in[0];
  const float* ipw  = (const float*)d_in[1];
  const float* ipb  = (const float*)d_in[2];
  const float* outw = (const float*)d_in[3];
  const float* outb = (const float*)d_in[4];
  const float* ln1g = (const float*)d_in[5];
  const float* ln1b = (const float*)d_in[6];
  const float* w1   = (const float*)d_in[7];
  const float* b1   = (const float*)d_in[8];
  const float* w2   = (const float*)d_in[9];
  const float* b2   = (const float*)d_in[10];
  const float* ln2g = (const float*)d_in[11];
  const float* ln2b = (const float*)d_in[12];
  float* out = (float*)d_out;

  bool wbf = (ws_size >= (size_t)WS_TOT * 2);
  if (wbf) {
    unsigned short* wsp = (unsigned short*)d_ws;
    hipLaunchKernelGGL(cvt_pack, dim3((442368+511)/512), dim3(512), 0, stream, ipw,  wsp + WS_IPW,  384,  442368);
    hipLaunchKernelGGL(cvt_pack, dim3((147456+511)/512), dim3(512), 0, stream, outw, wsp + WS_OUTW, 384,  147456);
    hipLaunchKernelGGL(cvt_pack, dim3((589824+511)/512), dim3(512), 0, stream, w1,   wsp + WS_W1,   384,  589824);
    hipLaunchKernelGGL(cvt_pack, dim3((589824+511)/512), dim3(512), 0, stream, w2,   wsp + WS_W2,   1536, 589824);
    (void)hipFuncSetAttribute((const void*)swin_mfma<true>,
                              hipFuncAttributeMaxDynamicSharedMemorySize, SMEM_BYTES);
    hipLaunchKernelGGL((swin_mfma<true>), dim3(1024), dim3(512), SMEM_BYTES, stream,
                       tokens, (const void*)(wsp + WS_IPW), ipb,
                       (const void*)(wsp + WS_OUTW), outb, ln1g, ln1b,
                       (const void*)(wsp + WS_W1), b1, (const void*)(wsp + WS_W2), b2,
                       ln2g, ln2b, out);
  } else {
    (void)hipFuncSetAttribute((const void*)swin_mfma<false>,
                              hipFuncAttributeMaxDynamicSharedMemorySize, SMEM_BYTES);
    hipLaunchKernelGGL((swin_mfma<false>), dim3(1024), dim3(512), SMEM_BYTES, stream,
                       tokens, (const void*)ipw, ipb, (const void*)outw, outb, ln1g, ln1b,
                       (const void*)w1, b1, (const void*)w2, b2, ln2g, ln2b, out);
  }
}

// Round 4
// 475.233 us; speedup vs baseline: 32.0552x; 1.0512x over previous
//
#include <hip/hip_runtime.h>
#include <hip/hip_bf16.h>
#include <math.h>

using short8 = __attribute__((ext_vector_type(8))) short;
using f32x4  = __attribute__((ext_vector_type(4))) float;

#define MFMA_B16(A,B,C) __builtin_amdgcn_mfma_f32_16x16x32_bf16((A),(B),(C),0,0,0)

// ---------------- LDS layout (bytes) ----------------
// aln [49][392]u16; q2/k2 [49][72]u16 (rows>=49 garbage: masked or discarded);
// vT2 [64][72]u16 (token cols>=49 zero-init, never overwritten); oh [64][72]u16
// (rows>=49 garbage -> discarded C rows). MLP: hid double-buffer [64][136]u16
// aliases q2..oh pool. Total 79 KiB -> 2 blocks/CU.
#define ALN_STR 392
#define Q2_OFF  38416
#define QK_STR  72
#define K2_OFF  45472
#define VT_OFF  52528
#define VT_STR  72
#define OH_OFF  61744
#define OH_STR  72
#define HID0_OFF 38416
#define HID1_OFF 55824
#define HID_STR 136
#define SMEM_BYTES 80896   // 79 KiB

__device__ __forceinline__ unsigned f2bf(float x) {   // RNE f32->bf16
  unsigned u = __float_as_uint(x);
  return (u + 0x7fffu + ((u >> 16) & 1u)) >> 16;
}

// B-operand load. WBF: packed fragment layout [tile][kchunk][lane][8] bf16 ->
// one coalesced 16B/lane read. !WBF: gather from f32 row-major + convert.
template<bool WBF>
__device__ __forceinline__ short8 loadW(const void* base, int tile, int K8, int kcb,
                                        int l, int row, int ldk, int k0) {
  if constexpr (WBF) {
    return *(const short8*)((const unsigned short*)base +
                            (((size_t)(tile * K8 + kcb)) << 7) + l * 8);
  } else {
    const float* p = (const float*)base + (size_t)row * ldk + k0;
    float4 x = *(const float4*)p;
    float4 y = *(const float4*)(p + 4);
    short8 r;
    r[0]=(short)f2bf(x.x); r[1]=(short)f2bf(x.y); r[2]=(short)f2bf(x.z); r[3]=(short)f2bf(x.w);
    r[4]=(short)f2bf(y.x); r[5]=(short)f2bf(y.y); r[6]=(short)f2bf(y.z); r[7]=(short)f2bf(y.w);
    return r;
  }
}

// Repack f32 [rows][K] -> bf16 fragment order [tile][kc][r16][8].
__global__ void cvt_pack(const float* __restrict__ src, unsigned short* __restrict__ dst,
                         int K, int n) {
  int K8 = K >> 3;
  int i = blockIdx.x * blockDim.x + threadIdx.x;
  if (i >= n) return;
  int e = i & 7;
  int idx = i >> 3;
  int r = idx & 15; idx >>= 4;
  int kc = idx % K8, ci = idx / K8;
  dst[i] = (unsigned short)f2bf(src[(size_t)(ci * 16 + r) * K + kc * 8 + e]);
}

template<bool WBF>
__global__ __launch_bounds__(512, 4)
void swin_mfma(const float* __restrict__ tokens,
               const void* __restrict__ ipw,  const float* __restrict__ ipb,
               const void* __restrict__ outw, const float* __restrict__ outb,
               const float* __restrict__ ln1g, const float* __restrict__ ln1b,
               const void* __restrict__ w1,   const float* __restrict__ b1,
               const void* __restrict__ w2,   const float* __restrict__ b2,
               const float* __restrict__ ln2g, const float* __restrict__ ln2b,
               float* __restrict__ out)
{
  extern __shared__ char smem[];
  unsigned short* aln  = (unsigned short*)smem;
  unsigned short* q2   = (unsigned short*)(smem + Q2_OFF);
  unsigned short* k2   = (unsigned short*)(smem + K2_OFF);
  unsigned short* vT2  = (unsigned short*)(smem + VT_OFF);
  unsigned short* oh   = (unsigned short*)(smem + OH_OFF);
  unsigned short* hid0 = (unsigned short*)(smem + HID0_OFF);
  unsigned short* hid1 = (unsigned short*)(smem + HID1_OFF);

  const int tid = threadIdx.x;
  const int l  = tid & 63, wv = tid >> 6;
  const int cl = l & 15,  kg = l >> 4;
  const int wid = blockIdx.x;
  const int iw = wid & 7, ih = (wid >> 3) & 7, bt = wid >> 6;

  auto gidx = [&](int r, int c) -> size_t {
    int wi = r / 7, wj = r - wi * 7;
    return ((size_t)bt * 3136 + (size_t)((ih*7 + wi) * 56 + iw*7 + wj)) * 384 + c;
  };

  auto ln_pass = [&](const float* src, const float* gw, const float* gb) {
    int grp = tid >> 3, lj = tid & 7;
    if (grp < 49) {
      size_t base = gidx(grp, 0);
      float4 xv[12];
      float sx = 0.f, sxx = 0.f;
      #pragma unroll
      for (int k = 0; k < 12; ++k) {
        xv[k] = *(const float4*)&src[base + (lj + 8*k) * 4];
        sx  += xv[k].x + xv[k].y + xv[k].z + xv[k].w;
        sxx += xv[k].x*xv[k].x + xv[k].y*xv[k].y + xv[k].z*xv[k].z + xv[k].w*xv[k].w;
      }
      #pragma unroll
      for (int d = 1; d < 8; d <<= 1) { sx += __shfl_xor(sx, d, 8); sxx += __shfl_xor(sxx, d, 8); }
      float mean = sx * (1.f/384.f);
      float rs = rsqrtf(sxx * (1.f/384.f) - mean*mean + 1e-5f);
      unsigned short* arow = aln + grp * ALN_STR;
      #pragma unroll
      for (int k = 0; k < 12; ++k) {
        int c = (lj + 8*k) * 4;
        float4 gv = *(const float4*)&gw[c];
        float4 bv = *(const float4*)&gb[c];
        unsigned u0 = f2bf((xv[k].x-mean)*rs*gv.x + bv.x) | (f2bf((xv[k].y-mean)*rs*gv.y + bv.y) << 16);
        unsigned u1 = f2bf((xv[k].z-mean)*rs*gv.z + bv.z) | (f2bf((xv[k].w-mean)*rs*gv.w + bv.w) << 16);
        *(uint2*)&arow[c] = make_uint2(u0, u1);
      }
    }
  };

  const int ri0 = wv & 3, chalf = wv >> 2;
  const int arow0 = (cl + 16 * ri0) * ALN_STR;

  // QKV for head pair pr: writes q2/k2/vT2 (rows<49 only).
  auto qkv = [&](int pr) {
    #pragma unroll
    for (int half = 0; half < 2; ++half) {
      int cia[3], tilea[3], growa[3];
      #pragma unroll
      for (int j = 0; j < 3; ++j) {
        int ci = chalf + 2 * (half * 3 + j);
        int part = ci >> 2, wt = ci & 3;
        cia[j] = ci;
        tilea[j] = part * 24 + pr * 4 + wt;
        growa[j] = part * 384 + pr * 64 + wt * 16 + cl;
      }
      f32x4 d0{0,0,0,0}, d1{0,0,0,0}, d2{0,0,0,0};
      #pragma unroll
      for (int kt = 0; kt < 12; ++kt) {
        int k0 = kt * 32 + kg * 8;
        short8 a = *(const short8*)&aln[arow0 + k0];
        short8 b0 = loadW<WBF>(ipw, tilea[0], 48, kt*4, l, growa[0], 384, k0);
        short8 b1 = loadW<WBF>(ipw, tilea[1], 48, kt*4, l, growa[1], 384, k0);
        short8 b2 = loadW<WBF>(ipw, tilea[2], 48, kt*4, l, growa[2], 384, k0);
        d0 = MFMA_B16(a, b0, d0);
        d1 = MFMA_B16(a, b1, d1);
        d2 = MFMA_B16(a, b2, d2);
      }
      #pragma unroll
      for (int j = 0; j < 3; ++j) {
        f32x4 dd = (j == 0) ? d0 : (j == 1) ? d1 : d2;
        int part = cia[j] >> 2;
        int within = (cia[j] & 3) * 16 + cl;
        float bias = ipb[growa[j]];
        float scl = (part == 0) ? 0.17677669529663687f : 1.f;
        #pragma unroll
        for (int rg = 0; rg < 4; ++rg) {
          int row = kg * 4 + rg + 16 * ri0;
          if (row < 49) {
            unsigned short bv = (unsigned short)f2bf((dd[rg] + bias) * scl);
            if      (part == 0) q2[row * QK_STR + within] = bv;
            else if (part == 1) k2[row * QK_STR + within] = bv;
            else                vT2[within * VT_STR + row] = bv;
          }
        }
      }
    }
  };

  // ---- init: zero vT2 pad (token cols >=49 must stay 0), LN1 ----
  for (int i = tid; i < (64*VT_STR)/2; i += 512) ((unsigned*)(smem + VT_OFF))[i] = 0u;
  ln_pass(tokens, ln1g, ln1b);
  __syncthreads();

  f32x4 opacc[3][4];
  #pragma unroll
  for (int a = 0; a < 3; ++a)
    #pragma unroll
    for (int b = 0; b < 4; ++b) opacc[a][b] = f32x4{0.f,0.f,0.f,0.f};

  qkv(0);
  __syncthreads();

  const int hl = wv & 1, qci = wv >> 1;   // wave's (head-within-pair, q col-tile)

  for (int pr = 0; pr < 6; ++pr) {
    // ---- P_a: scores (swapped: mfma(K,Q)) + in-register softmax + PV ----
    {
      short8 bq = *(const short8*)&q2[(16*qci + cl) * QK_STR + hl*32 + kg*8];
      f32x4 dsc[4];
      #pragma unroll
      for (int kri = 0; kri < 4; ++kri) {
        short8 ak = *(const short8*)&k2[(16*kri + cl) * QK_STR + hl*32 + kg*8];
        f32x4 z{0.f,0.f,0.f,0.f};
        dsc[kri] = MFMA_B16(ak, bq, z);
      }
      // lane (cl,kg) holds scores(k=16kri+4kg+r, q=16qci+cl); mask k>=49
      float ev[4][4];
      float mx = -1e30f;
      #pragma unroll
      for (int kri = 0; kri < 4; ++kri)
        #pragma unroll
        for (int r = 0; r < 4; ++r) {
          int kidx = 16*kri + 4*kg + r;
          float v = (kidx < 49) ? dsc[kri][r] : -1e30f;
          ev[kri][r] = v;
          mx = fmaxf(mx, v);
        }
      mx = fmaxf(mx, __shfl_xor(mx, 16));
      mx = fmaxf(mx, __shfl_xor(mx, 32));
      float sum = 0.f;
      #pragma unroll
      for (int kri = 0; kri < 4; ++kri)
        #pragma unroll
        for (int r = 0; r < 4; ++r) {
          float e = __expf(ev[kri][r] - mx);
          ev[kri][r] = e; sum += e;
        }
      sum += __shfl_xor(sum, 16);
      sum += __shfl_xor(sum, 32);
      float inv = 1.f / sum;
      unsigned pk[4][2];
      #pragma unroll
      for (int kri = 0; kri < 4; ++kri) {
        pk[kri][0] = f2bf(ev[kri][0]*inv) | (f2bf(ev[kri][1]*inv) << 16);
        pk[kri][1] = f2bf(ev[kri][2]*inv) | (f2bf(ev[kri][3]*inv) << 16);
      }
      // PV (swapped: mfma(vT, P)) -> oh^T; P B-frags built by shuffles
      f32x4 dot0{0.f,0.f,0.f,0.f}, dot1{0.f,0.f,0.f,0.f};
      const int sA = cl + 32 * (kg & 1);
      const bool hi = (kg >> 1) & 1;
      #pragma unroll
      for (int kt = 0; kt < 2; ++kt) {
        unsigned x0 = (unsigned)__shfl((int)pk[2*kt][0],   sA);
        unsigned x1 = (unsigned)__shfl((int)pk[2*kt][1],   sA);
        unsigned x2 = (unsigned)__shfl((int)pk[2*kt][0],   sA + 16);
        unsigned x3 = (unsigned)__shfl((int)pk[2*kt][1],   sA + 16);
        unsigned y0 = (unsigned)__shfl((int)pk[2*kt+1][0], sA);
        unsigned y1 = (unsigned)__shfl((int)pk[2*kt+1][1], sA);
        unsigned y2 = (unsigned)__shfl((int)pk[2*kt+1][0], sA + 16);
        unsigned y3 = (unsigned)__shfl((int)pk[2*kt+1][1], sA + 16);
        uint4 bu = make_uint4(hi ? y0 : x0, hi ? y1 : x1, hi ? y2 : x2, hi ? y3 : x3);
        short8 bfrag = *(short8*)&bu;
        short8 a0 = *(const short8*)&vT2[(hl*32 +  0 + cl) * VT_STR + kt*32 + kg*8];
        short8 a1 = *(const short8*)&vT2[(hl*32 + 16 + cl) * VT_STR + kt*32 + kg*8];
        dot0 = MFMA_B16(a0, bfrag, dot0);
        dot1 = MFMA_B16(a1, bfrag, dot1);
      }
      int q = 16*qci + cl;
      if (q < 49) {
        int base = q * OH_STR + hl*32 + kg*4;
        *(unsigned*)&oh[base     ] = f2bf(dot0[0]) | (f2bf(dot0[1]) << 16);
        *(unsigned*)&oh[base +  2] = f2bf(dot0[2]) | (f2bf(dot0[3]) << 16);
        *(unsigned*)&oh[base + 16] = f2bf(dot1[0]) | (f2bf(dot1[1]) << 16);
        *(unsigned*)&oh[base + 18] = f2bf(dot1[2]) | (f2bf(dot1[3]) << 16);
      }
    }
    __syncthreads();

    // ---- P_b: out-proj(pr) (K=64, both heads) + QKV(pr+1) ----
    {
      short8 ao[4][2];
      #pragma unroll
      for (int ri = 0; ri < 4; ++ri)
        #pragma unroll
        for (int kt = 0; kt < 2; ++kt)
          ao[ri][kt] = *(const short8*)&oh[(cl + 16*ri) * OH_STR + kt*32 + kg*8];
      #pragma unroll
      for (int cii = 0; cii < 3; ++cii) {
        #pragma unroll
        for (int kt = 0; kt < 2; ++kt) {
          short8 bw = loadW<WBF>(outw, wv*3 + cii, 48, pr*8 + kt*4, l,
                                 (wv*3 + cii)*16 + cl, 384, pr*64 + kt*32 + kg*8);
          opacc[cii][0] = MFMA_B16(ao[0][kt], bw, opacc[cii][0]);
          opacc[cii][1] = MFMA_B16(ao[1][kt], bw, opacc[cii][1]);
          opacc[cii][2] = MFMA_B16(ao[2][kt], bw, opacc[cii][2]);
          opacc[cii][3] = MFMA_B16(ao[3][kt], bw, opacc[cii][3]);
        }
      }
      if (pr < 5) qkv(pr + 1);
    }
    __syncthreads();
  }

  // ---- win = tokens + attn + out_b -> out ----
  #pragma unroll
  for (int cii = 0; cii < 3; ++cii) {
    int col = (wv*3 + cii) * 16 + cl;
    float ob = outb[col];
    #pragma unroll
    for (int ri = 0; ri < 4; ++ri) {
      #pragma unroll
      for (int rg = 0; rg < 4; ++rg) {
        int row = kg*4 + rg + 16*ri;
        if (row < 49) {
          size_t g = gidx(row, col);
          out[g] = tokens[g] + opacc[cii][ri][rg] + ob;
        }
      }
    }
  }
  __syncthreads();

  // ---- LN2 ----
  ln_pass(out, ln2g, ln2b);
  __syncthreads();

  // ---- MLP: double-buffered hid, MLP2(cc-1)+MLP1(cc) per phase ----
  f32x4 macc[3][4];
  #pragma unroll
  for (int a = 0; a < 3; ++a)
    #pragma unroll
    for (int b = 0; b < 4; ++b) macc[a][b] = f32x4{0.f,0.f,0.f,0.f};

  auto mlp1 = [&](int cc, unsigned short* hb) {
    int tile = cc * 8 + wv;
    int n = cc * 128 + wv * 16 + cl;
    f32x4 e0{0,0,0,0}, e1{0,0,0,0}, e2{0,0,0,0}, e3{0,0,0,0};
    #pragma unroll
    for (int kt = 0; kt < 12; ++kt) {
      int k0 = kt * 32 + kg * 8;
      short8 bw = loadW<WBF>(w1, tile, 48, kt*4, l, n, 384, k0);
      short8 a0 = *(const short8*)&aln[(cl     ) * ALN_STR + k0];
      short8 a1 = *(const short8*)&aln[(cl + 16) * ALN_STR + k0];
      short8 a2 = *(const short8*)&aln[(cl + 32) * ALN_STR + k0];
      short8 a3 = *(const short8*)&aln[(cl + 48) * ALN_STR + k0];
      e0 = MFMA_B16(a0, bw, e0);
      e1 = MFMA_B16(a1, bw, e1);
      e2 = MFMA_B16(a2, bw, e2);
      e3 = MFMA_B16(a3, bw, e3);
    }
    float bb = b1[n];
    #pragma unroll
    for (int ri = 0; ri < 4; ++ri) {
      f32x4 ee = (ri == 0) ? e0 : (ri == 1) ? e1 : (ri == 2) ? e2 : e3;
      #pragma unroll
      for (int rg = 0; rg < 4; ++rg) {
        int row = kg*4 + rg + 16*ri;
        if (row < 49) {
          float x = ee[rg] + bb;
          float gl = 0.5f * x * (1.f + erff(x * 0.70710678118654752f));
          hb[row * HID_STR + wv*16 + cl] = (unsigned short)f2bf(gl);
        }
      }
    }
  };
  auto mlp2 = [&](int cc, const unsigned short* hb) {
    #pragma unroll
    for (int kt = 0; kt < 4; ++kt) {
      int k0 = kt * 32 + kg * 8;
      short8 h0_ = *(const short8*)&hb[(cl     ) * HID_STR + k0];
      short8 h1_ = *(const short8*)&hb[(cl + 16) * HID_STR + k0];
      short8 h2_ = *(const short8*)&hb[(cl + 32) * HID_STR + k0];
      short8 h3_ = *(const short8*)&hb[(cl + 48) * HID_STR + k0];
      #pragma unroll
      for (int cii = 0; cii < 3; ++cii) {
        short8 bw = loadW<WBF>(w2, wv*3 + cii, 192, cc*16 + kt*4, l,
                               (wv*3 + cii)*16 + cl, 1536, cc*128 + k0);
        macc[cii][0] = MFMA_B16(h0_, bw, macc[cii][0]);
        macc[cii][1] = MFMA_B16(h1_, bw, macc[cii][1]);
        macc[cii][2] = MFMA_B16(h2_, bw, macc[cii][2]);
        macc[cii][3] = MFMA_B16(h3_, bw, macc[cii][3]);
      }
    }
  };

  mlp1(0, hid0);
  __syncthreads();
  for (int cc = 1; cc < 12; ++cc) {
    mlp2(cc - 1, ((cc - 1) & 1) ? hid1 : hid0);
    mlp1(cc, (cc & 1) ? hid1 : hid0);
    __syncthreads();
  }
  mlp2(11, hid1);

  // ---- final: out += mlp + b2 ----
  #pragma unroll
  for (int cii = 0; cii < 3; ++cii) {
    int col = (wv*3 + cii) * 16 + cl;
    float bb2 = b2[col];
    #pragma unroll
    for (int ri = 0; ri < 4; ++ri) {
      #pragma unroll
      for (int rg = 0; rg < 4; ++rg) {
        int row = kg*4 + rg + 16*ri;
        if (row < 49) {
          size_t g = gidx(row, col);
          out[g] = out[g] + macc[cii][ri][rg] + bb2;
        }
      }
    }
  }
}

// ws layout (bf16 elements): ipw[442368] | outw[147456] | w1[589824] | w2[589824]
#define WS_IPW  0
#define WS_OUTW 442368
#define WS_W1   589824
#define WS_W2   1179648
#define WS_TOT  1769472

extern "C" void kernel_launch(void* const* d_in, const int* in_sizes, int n_in,
                              void* d_out, int out_size, void* d_ws, size_t ws_size,
                              hipStream_t stream) {
  (void)in_sizes; (void)n_in; (void)out_size;
  const float* tokens = (const float*)d_in[0];
  const float* ipw  = (const float*)d_in[1];
  const float* ipb  = (const float*)d_in[2];
  const float* outw = (const float*)d_in[3];
  const float* outb = (const float*)d_in[4];
  const float* ln1g = (const float*)d_in[5];
  const float* ln1b = (const float*)d_in[6];
  const float* w1   = (const float*)d_in[7];
  const float* b1   = (const float*)d_in[8];
  const float* w2   = (const float*)d_in[9];
  const float* b2   = (const float*)d_in[10];
  const float* ln2g = (const float*)d_in[11];
  const float* ln2b = (const float*)d_in[12];
  float* out = (float*)d_out;

  bool wbf = (ws_size >= (size_t)WS_TOT * 2);
  if (wbf) {
    unsigned short* wsp = (unsigned short*)d_ws;
    hipLaunchKernelGGL(cvt_pack, dim3((442368+511)/512), dim3(512), 0, stream, ipw,  wsp + WS_IPW,  384,  442368);
    hipLaunchKernelGGL(cvt_pack, dim3((147456+511)/512), dim3(512), 0, stream, outw, wsp + WS_OUTW, 384,  147456);
    hipLaunchKernelGGL(cvt_pack, dim3((589824+511)/512), dim3(512), 0, stream, w1,   wsp + WS_W1,   384,  589824);
    hipLaunchKernelGGL(cvt_pack, dim3((589824+511)/512), dim3(512), 0, stream, w2,   wsp + WS_W2,   1536, 589824);
    (void)hipFuncSetAttribute((const void*)swin_mfma<true>,
                              hipFuncAttributeMaxDynamicSharedMemorySize, SMEM_BYTES);
    hipLaunchKernelGGL((swin_mfma<true>), dim3(1024), dim3(512), SMEM_BYTES, stream,
                       tokens, (const void*)(wsp + WS_IPW), ipb,
                       (const void*)(wsp + WS_OUTW), outb, ln1g, ln1b,
                       (const void*)(wsp + WS_W1), b1, (const void*)(wsp + WS_W2), b2,
                       ln2g, ln2b, out);
  } else {
    (void)hipFuncSetAttribute((const void*)swin_mfma<false>,
                              hipFuncAttributeMaxDynamicSharedMemorySize, SMEM_BYTES);
    hipLaunchKernelGGL((swin_mfma<false>), dim3(1024), dim3(512), SMEM_BYTES, stream,
                       tokens, (const void*)ipw, ipb, (const void*)outw, outb, ln1g, ln1b,
                       (const void*)w1, b1, (const void*)w2, b2, ln2g, ln2b, out);
  }
}